// Round 1
// 270.538 us; speedup vs baseline: 1.1103x; 1.1103x over previous
//
#include <hip/hip_runtime.h>
#include <math.h>

// Problem constants
#define CC 3
#define HH 1280
#define WW 720
#define BSZ 20
#define NHB 64
#define NWB 36
#define NBLK (NHB*NWB)          // 2304
#define OUT_IMG (3*5120*2880)   // 44236800

#define SLAB_PITCH 84           // 80 cols + pad; 84 % 32 = 20 -> row-bank offsets all distinct for |drow|<8
#define SLAB_ROWS  60           // 3 c * 20 out-rows per slab

// Union'd LDS: light and gate are block-uniform branches of one kernel.
union __align__(16) SMem {
  struct {
    float in_s[3][22][24];             // zero-padded input block (rows padded to 24)
    float w_s[48*27 + 48];
    float slab[SLAB_ROWS][SLAB_PITCH]; // pixel-shuffled output slab (transpose buffer)
  } L;                                  // 31872 B
  struct {
    float ins[3][26][28];              // clamped input patch (edge pad baked in)
    float w1s[16*27];
    float b1s[16];
    float w2s[8*16*9];
    float b2s[8];
    float w3s[200];                    // sum of dwords before x1s is even -> x1s 8B-aligned
    float x1s[16][12][14];             // post-pool conv1 patch, cols padded to 14 (8B-aligned float2)
    float red[256];
    float b3s;
  } G;                                  // 27.8 KB
};

// ---------------------------------------------------------------------------
// Light expert: per 20x20 block, zero-pad conv3x3 (3->48) + pixel_shuffle(4)
// + clamp[0,0.6]+0.4. mask is always False -> complex expert dead.
// NEW: results staged through an LDS slab so global stores are float4-coalesced
// (was: 20 scalar stores/thread at 16B stride -> 16-line scatter per wave).
// ---------------------------------------------------------------------------
__device__ __forceinline__ void light_body(
    SMem& sm, int l,
    const float* __restrict__ inp,
    const float* __restrict__ wl,
    const float* __restrict__ bl,
    float* __restrict__ out) {
  const int bi = l / NWB, bj = l % NWB;
  const int tid = threadIdx.x;
  float* w_s = sm.L.w_s;

  for (int i = tid; i < 3*22*24; i += 256) ((float*)sm.L.in_s)[i] = 0.0f;
  for (int i = tid; i < 48*27; i += 256) w_s[i] = wl[i];
  if (tid < 48) w_s[48*27 + tid] = bl[tid];
  __syncthreads();
  // stage 20x20x3 block; global float4 loads (WW=720 and 20*bj are mult of 4)
  for (int i = tid; i < 300; i += 256) {
    int x4 = i % 5; int r = (i / 5) % 20; int c = i / 100;
    const float4 v = *(const float4*)&inp[(c*HH + bi*BSZ + r)*WW + bj*BSZ + 4*x4];
    float* dst = &sm.L.in_s[c][r+1][1 + 4*x4];
    dst[0] = v.x; dst[1] = v.y; dst[2] = v.z; dst[3] = v.w;
  }
  __syncthreads();

  const int row0 = bi * 80, col0 = bj * 80;

  // 4 slabs of 5 conv-rows each: 48 oc * 5 h = 240 pairs per slab
  for (int slab = 0; slab < 4; ++slab) {
    if (tid < 240) {
      const int oc = tid % 48;
      const int hl = tid / 48;
      const int h  = slab*5 + hl;
      float wr[27];
      #pragma unroll
      for (int j = 0; j < 27; ++j) wr[j] = w_s[oc*27 + j];
      float acc[20];
      const float bias = w_s[48*27 + oc];
      #pragma unroll
      for (int w = 0; w < 20; ++w) acc[w] = bias;

      #pragma unroll
      for (int ic = 0; ic < 3; ++ic)
        #pragma unroll
        for (int ky = 0; ky < 3; ++ky) {
          const float* row = &sm.L.in_s[ic][h + ky][0];
          float r[24];
          #pragma unroll
          for (int j = 0; j < 6; ++j) {
            float4 v = ((const float4*)row)[j];   // ds_read_b128, same-addr broadcast across lanes
            r[j*4+0] = v.x; r[j*4+1] = v.y; r[j*4+2] = v.z; r[j*4+3] = v.w;
          }
          const float w0 = wr[ic*9 + ky*3 + 0];
          const float w1 = wr[ic*9 + ky*3 + 1];
          const float w2 = wr[ic*9 + ky*3 + 2];
          #pragma unroll
          for (int w = 0; w < 20; ++w)
            acc[w] += r[w]*w0 + r[w+1]*w1 + r[w+2]*w2;
        }

      // pixel_shuffle scatter -> LDS slab (cheap: ds_write_b32, <=2-way banks)
      // out[c][h*4+r1][w*4+r2] => slab[c*20 + hl*4 + r1][r2 + 4w]
      const int c  = oc >> 4;
      const int r1 = (oc >> 2) & 3;
      const int r2 = oc & 3;
      float* dst = &sm.L.slab[c*20 + hl*4 + r1][r2];
      #pragma unroll
      for (int w = 0; w < 20; ++w)
        dst[4*w] = fminf(fmaxf(acc[w], 0.0f), 0.6f) + 0.4f;
    }
    __syncthreads();

    // coalesced writeback: 60 rows x 20 float4 (320B contiguous per row segment)
    for (int i = tid; i < SLAB_ROWS*20; i += 256) {
      const int rrow = i / 20, cb = i % 20;
      const int c = rrow / 20, lr = rrow % 20;
      const float4 v = *(const float4*)&sm.L.slab[rrow][4*cb];
      const int gy = row0 + slab*20 + lr;
      *(float4*)&out[(c*5120 + gy)*2880 + col0 + 4*cb] = v;
    }
    __syncthreads();
  }
}

// ---------------------------------------------------------------------------
// Fused gate CNN (unchanged math; float2 LDS reads to halve DS-pipe traffic):
//   stage A: conv1(3->16, edge-pad) + tanh + maxpool2 on a local 12x12 patch
//   stage B: conv2(16->8, edge-pad) + maxpool2 -> 8x5x5 window
//   stage C: 5x5x8 dot (conv3 stride 5) + sigmoid -> 1 scalar
// ---------------------------------------------------------------------------
__device__ __forceinline__ void gate_body(
    SMem& sm, int l,
    const float* __restrict__ inp,
    const float* __restrict__ w1,
    const float* __restrict__ b1,
    const float* __restrict__ w2,
    const float* __restrict__ b2,
    const float* __restrict__ w3,
    const float* __restrict__ b3,
    float* __restrict__ cv) {
  const int tid = threadIdx.x;
  const int oy = l / NWB, ox = l % NWB;

  for (int i = tid; i < 16*27; i += 256) sm.G.w1s[i] = w1[i];
  for (int i = tid; i < 8*16*9; i += 256) sm.G.w2s[i] = w2[i];
  for (int i = tid; i < 200; i += 256) sm.G.w3s[i] = w3[i];
  if (tid < 16) sm.G.b1s[tid] = b1[tid];
  if (tid < 8)  sm.G.b2s[tid] = b2[tid];
  if (tid == 0) sm.G.b3s = b3[0];

  // input patch rows [20*oy-3, 20*oy+23), cols [20*ox-3, 20*ox+23), clamped
  for (int i = tid; i < 3*26*28; i += 256) {
    int b = i % 28; int a = (i / 28) % 26; int ic = i / (26*28);
    int gy = 20*oy - 3 + a; gy = gy < 0 ? 0 : (gy > HH-1 ? HH-1 : gy);
    int gx = 20*ox - 3 + b; gx = gx < 0 ? 0 : (gx > WW-1 ? WW-1 : gx);
    sm.G.ins[ic][a][b] = inp[(ic*HH + gy)*WW + gx];
  }
  __syncthreads();

  // ---- stage A
  for (int v = tid; v < 16*12*12; v += 256) {
    int oc = v / 144; int rem = v - oc*144; int ly = rem / 12; int lx = rem - ly*12;
    int y1 = 10*oy - 1 + ly; y1 = y1 < 0 ? 0 : (y1 > 639 ? 639 : y1);
    int x1 = 10*ox - 1 + lx; x1 = x1 < 0 ? 0 : (x1 > 359 ? 359 : x1);
    int ry = 2*y1 + 2 - 20*oy;   // local row of conv input patch, even, in [0,22]
    int rx = 2*x1 + 2 - 20*ox;   // even, in [0,24]
    float patch[3][4][4];
    #pragma unroll
    for (int ic = 0; ic < 3; ++ic)
      #pragma unroll
      for (int d = 0; d < 4; ++d) {
        const float2 pa = *(const float2*)&sm.G.ins[ic][ry + d][rx];
        const float2 pb = *(const float2*)&sm.G.ins[ic][ry + d][rx + 2];
        patch[ic][d][0] = pa.x; patch[ic][d][1] = pa.y;
        patch[ic][d][2] = pb.x; patch[ic][d][3] = pb.y;
      }
    float m = -1e30f;
    #pragma unroll
    for (int sy = 0; sy < 2; ++sy)
      #pragma unroll
      for (int sx = 0; sx < 2; ++sx) {
        float acc = sm.G.b1s[oc];
        #pragma unroll
        for (int ic = 0; ic < 3; ++ic)
          #pragma unroll
          for (int ky = 0; ky < 3; ++ky)
            #pragma unroll
            for (int kx = 0; kx < 3; ++kx)
              acc += patch[ic][sy+ky][sx+kx] * sm.G.w1s[(oc*3+ic)*9 + ky*3 + kx];
        m = fmaxf(m, acc);
      }
    // tanh monotonic: maxpool(tanh(.)) == tanh(maxpool(.))
    sm.G.x1s[oc][ly][lx] = tanhf(m);
  }
  __syncthreads();

  // ---- stage B
  float prod = 0.0f;
  if (tid < 200) {
    int oc2 = tid / 25; int rem = tid - oc2*25; int j = rem / 5; int i5 = rem - j*5;
    float a00 = sm.G.b2s[oc2], a01 = a00, a10 = a00, a11 = a00;
    for (int ic = 0; ic < 16; ++ic) {
      float p[4][4];
      #pragma unroll
      for (int d = 0; d < 4; ++d) {
        const float2 pa = *(const float2*)&sm.G.x1s[ic][2*j + d][2*i5];
        const float2 pb = *(const float2*)&sm.G.x1s[ic][2*j + d][2*i5 + 2];
        p[d][0] = pa.x; p[d][1] = pa.y; p[d][2] = pb.x; p[d][3] = pb.y;
      }
      #pragma unroll
      for (int ky = 0; ky < 3; ++ky)
        #pragma unroll
        for (int kx = 0; kx < 3; ++kx) {
          float wv = sm.G.w2s[((oc2*16 + ic)*3 + ky)*3 + kx];
          a00 += p[ky  ][kx  ]*wv;
          a01 += p[ky  ][kx+1]*wv;
          a10 += p[ky+1][kx  ]*wv;
          a11 += p[ky+1][kx+1]*wv;
        }
    }
    float x2 = fmaxf(fmaxf(a00, a01), fmaxf(a10, a11));
    prod = x2 * sm.G.w3s[tid];          // w3 index (oc2*5+j)*5+i5 == tid
  }
  sm.G.red[tid] = prod;
  __syncthreads();

  // ---- stage C
  if (tid < 64) {
    float s = sm.G.red[tid] + sm.G.red[tid+64] + sm.G.red[tid+128] + sm.G.red[tid+192];
    #pragma unroll
    for (int off = 32; off > 0; off >>= 1) s += __shfl_down(s, off);
    if (tid == 0)
      cv[l] = 1.0f / (1.0f + expf(-(s + sm.G.b3s)));
  }
}

// ---------------------------------------------------------------------------
// One launch, interleaved light/gate blocks (block-uniform branch) so the two
// independent kernels overlap instead of serializing on the stream.
// ---------------------------------------------------------------------------
__global__ __launch_bounds__(256) void fused_kernel(
    const float* __restrict__ inp,
    const float* __restrict__ w1,
    const float* __restrict__ b1,
    const float* __restrict__ w2,
    const float* __restrict__ b2,
    const float* __restrict__ w3,
    const float* __restrict__ b3,
    const float* __restrict__ wl,
    const float* __restrict__ bl,
    float* __restrict__ out) {
  __shared__ SMem sm;
  const int bid = blockIdx.x;
  if (bid & 1)
    gate_body(sm, bid >> 1, inp, w1, b1, w2, b2, w3, b3, out + OUT_IMG);
  else
    light_body(sm, bid >> 1, inp, wl, bl, out);
}

// ---------------------------------------------------------------------------
extern "C" void kernel_launch(void* const* d_in, const int* in_sizes, int n_in,
                              void* d_out, int out_size, void* d_ws, size_t ws_size,
                              hipStream_t stream) {
  const float* inp = (const float*)d_in[0];
  const float* w1  = (const float*)d_in[1];
  const float* b1  = (const float*)d_in[2];
  const float* w2  = (const float*)d_in[3];
  const float* b2  = (const float*)d_in[4];
  const float* w3  = (const float*)d_in[5];
  const float* b3  = (const float*)d_in[6];
  const float* wl  = (const float*)d_in[7];
  const float* bl  = (const float*)d_in[8];
  // d_in[9..14] = wc1,bc1,wc2,bc2,wc3,bc3: dead (gate sigmoid <= 1 -> mask always False)

  float* out = (float*)d_out;

  hipLaunchKernelGGL(fused_kernel, dim3(2*NBLK), dim3(256), 0, stream,
                     inp, w1, b1, w2, b2, w3, b3, wl, bl, out);
}